// Round 1
// baseline (6820.428 us; speedup 1.0000x reference)
//
#include <hip/hip_runtime.h>
#include <math.h>

#define NTOK 200704          // B*S = 4096*49
#define CDIM 384
#define NH3 1152             // 3*C
#define NHEADS 12
#define HD 32
#define SEQ 49
#define QL 77070336          // CDIM*NTOK (one third of T)

__device__ __forceinline__ float gelu_exact(float x) {
    return 0.5f * x * (1.0f + erff(x * 0.70710678118654752f));
}

// C = gelu(A @ W + bias). A: MxK row-major, W: KxN row-major.
// TRANS_OUT: write out[n*M + m] (transposed) else out[m*N + n].
template<int BM, int BN, int BK, bool TRANS_OUT>
__global__ __launch_bounds__(256)
void gemm_gelu(const float* __restrict__ A, const float* __restrict__ W,
               const float* __restrict__ bias, float* __restrict__ out,
               int M, int N, int K) {
    __shared__ float As[BK][BM];
    __shared__ float Bs[BK][BN];
    const int tid = threadIdx.x;
    const int m0 = blockIdx.x * BM;
    const int n0 = blockIdx.y * BN;
    const int tm = tid / (BN / 4);   // 0..15
    const int tn = tid % (BN / 4);   // 0..15

    float acc[4][4] = {};
    for (int k0 = 0; k0 < K; k0 += BK) {
        #pragma unroll
        for (int i = tid; i < BM * BK; i += 256) {
            int m = i / BK, k = i % BK;
            As[k][m] = A[(size_t)(m0 + m) * K + k0 + k];
        }
        #pragma unroll
        for (int i = tid; i < BK * BN; i += 256) {
            int k = i / BN, n = i % BN;
            Bs[k][n] = W[(size_t)(k0 + k) * N + n0 + n];
        }
        __syncthreads();
        #pragma unroll
        for (int kk = 0; kk < BK; ++kk) {
            float4 a4 = *reinterpret_cast<const float4*>(&As[kk][tm * 4]);
            float4 b4 = *reinterpret_cast<const float4*>(&Bs[kk][tn * 4]);
            float a[4] = {a4.x, a4.y, a4.z, a4.w};
            float b[4] = {b4.x, b4.y, b4.z, b4.w};
            #pragma unroll
            for (int i = 0; i < 4; ++i)
                #pragma unroll
                for (int j = 0; j < 4; ++j)
                    acc[i][j] += a[i] * b[j];
        }
        __syncthreads();
    }
    #pragma unroll
    for (int i = 0; i < 4; ++i) {
        int m = m0 + tm * 4 + i;
        #pragma unroll
        for (int j = 0; j < 4; ++j) {
            int n = n0 + tn * 4 + j;
            float v = gelu_exact(acc[i][j] + bias[n]);
            if (TRANS_OUT) out[(size_t)n * M + m] = v;
            else           out[(size_t)m * N + n] = v;
        }
    }
}

// One block per (window b2, head h). T is the transposed gelu(qkv) tensor
// (3C x NTOK) flattened; q/k/v fragments are contiguous slices of it.
__global__ __launch_bounds__(256)
void attn_kernel(const float* __restrict__ T, const float* __restrict__ bias_table,
                 float* __restrict__ out) {
    const int b2 = blockIdx.x;
    const int h  = blockIdx.y;
    const size_t base = (size_t)b2 * 18816 + (size_t)h * 1568;

    __shared__ float q [SEQ][HD + 1];
    __shared__ float kk[SEQ][HD + 1];
    __shared__ float vv[SEQ][HD + 1];
    __shared__ float sc[SEQ][SEQ + 1];

    const int tid = threadIdx.x;
    for (int i = tid; i < SEQ * HD; i += 256) {
        int s = i / HD, d = i % HD;
        q [s][d] = T[base + i];
        kk[s][d] = T[(size_t)QL + base + i];
        vv[s][d] = T[2 * (size_t)QL + base + i];
    }
    __syncthreads();

    // scores + bias
    for (int i = tid; i < SEQ * SEQ; i += 256) {
        int s = i / SEQ, t = i % SEQ;
        float acc = 0.f;
        #pragma unroll
        for (int d = 0; d < HD; ++d) acc += q[s][d] * kk[t][d];
        int rel = 13 * ((t % 7) - (s % 7) + (t / 7) - (s / 7) + 12);
        sc[s][t] = acc + bias_table[rel * NHEADS + h];
    }
    __syncthreads();

    // softmax per row (49 rows; threads 0..48)
    if (tid < SEQ) {
        float mx = -1e30f;
        #pragma unroll
        for (int t = 0; t < SEQ; ++t) mx = fmaxf(mx, sc[tid][t]);
        float sum = 0.f;
        #pragma unroll
        for (int t = 0; t < SEQ; ++t) { float e = __expf(sc[tid][t] - mx); sc[tid][t] = e; sum += e; }
        float inv = 1.0f / sum;
        #pragma unroll
        for (int t = 0; t < SEQ; ++t) sc[tid][t] *= inv;
    }
    __syncthreads();

    // PV -> out[b2*49+s, h*32+d]  (the reference's bshd layout)
    for (int i = tid; i < SEQ * HD; i += 256) {
        int s = i / HD, d = i % HD;
        float acc = 0.f;
        #pragma unroll
        for (int t = 0; t < SEQ; ++t) acc += sc[s][t] * vv[t][d];
        int n = b2 * SEQ + s;
        out[(size_t)n * CDIM + h * HD + d] = acc;
    }
}

extern "C" void kernel_launch(void* const* d_in, const int* in_sizes, int n_in,
                              void* d_out, int out_size, void* d_ws, size_t ws_size,
                              hipStream_t stream) {
    const float* x          = (const float*)d_in[0];
    const float* w_qkv      = (const float*)d_in[1];
    const float* b_qkv      = (const float*)d_in[2];
    const float* bias_table = (const float*)d_in[3];
    const float* w_out      = (const float*)d_in[4];
    const float* b_out      = (const float*)d_in[5];
    float* out = (float*)d_out;
    float* T   = (float*)d_ws;    // needs 3*QL floats = 924.8 MB

    dim3 blk(256);

    // 1) T = transpose(gelu(x @ w_qkv + b_qkv))   (3C x NTOK)
    gemm_gelu<64, 64, 16, true><<<dim3(NTOK / 64, NH3 / 64), blk, 0, stream>>>(
        x, w_qkv, b_qkv, T, NTOK, NH3, CDIM);

    // 2) attention -> d_out used as staging Y0 (NTOK x C)
    attn_kernel<<<dim3(4096, NHEADS), blk, 0, stream>>>(T, bias_table, out);

    // 3) Y1 = gelu(Y0 @ w_out + b_out) -> reuse first third of T
    gemm_gelu<64, 64, 16, false><<<dim3(NTOK / 64, CDIM / 64), blk, 0, stream>>>(
        out, w_out, b_out, T, NTOK, CDIM, CDIM);

    // 4) out = gelu(Y1 @ w_out + b_out)
    gemm_gelu<64, 64, 16, false><<<dim3(NTOK / 64, CDIM / 64), blk, 0, stream>>>(
        T, w_out, b_out, out, NTOK, CDIM, CDIM);
}

// Round 2
// 2530.625 us; speedup vs baseline: 2.6952x; 2.6952x over previous
//
#include <hip/hip_runtime.h>
#include <math.h>

#define NTOK 200704          // B*S = 4096*49
#define CDIM 384
#define NH3 1152             // 3*C
#define NHEADS 12
#define HD 32
#define SEQ 49
#define QL 77070336ULL       // CDIM*NTOK (one third of T)

typedef __attribute__((ext_vector_type(8))) short short8;
typedef __attribute__((ext_vector_type(4))) float f32x4;

__device__ __forceinline__ float gelu_exact(float x) {
    return 0.5f * x * (1.0f + erff(x * 0.70710678118654752f));
}

// round-to-nearest-even bf16, returned as fp32 bit pattern (low 16 zero)
__device__ __forceinline__ unsigned bf16rn(float x) {
    unsigned u = __float_as_uint(x);
    return (u + 0x7fffu + ((u >> 16) & 1u)) & 0xffff0000u;
}

__device__ __forceinline__ void bf16split(float x, unsigned &h, unsigned &l) {
    unsigned hu = bf16rn(x);
    h = hu >> 16;
    float r = x - __uint_as_float(hu);
    l = bf16rn(r) >> 16;
}

union FragU { short8 v; uint2 u2[2]; };

// out[m][n] = gelu( sum_k A[m][k]*B[n][k]... with source layouts:
//   A_TRANS: A source is K x M (tile rows m are columns) ; else A is M x K
//   B_TRANS: B source is K x N                           ; else B is N x K
// bf16x3 split-precision MFMA. Tile 128x128, BK=32, 256 threads (4 waves 2x2).
template<bool A_TRANS, bool B_TRANS, bool BIAS_ROW>
__global__ __launch_bounds__(256, 2)
void gemm_b3(const float* __restrict__ A, const float* __restrict__ Bm,
             const float* __restrict__ bias, float* __restrict__ out,
             int M, int N, int K) {
    __shared__ unsigned short Ah[128 * 32], Al[128 * 32];
    __shared__ unsigned short Bh[128 * 32], Bl[128 * 32];

    const int tid = threadIdx.x;
    const int m0 = (A_TRANS ? blockIdx.x : blockIdx.y) * 128;
    const int n0 = (A_TRANS ? blockIdx.y : blockIdx.x) * 128;

    const int wid = tid >> 6, lane = tid & 63;
    const int wm = wid >> 1, wn = wid & 1;
    const int r15 = lane & 15, q = lane >> 4;

    // staging index precompute
    const int d_row = tid >> 3;      // direct: row within 32-row group
    const int d_f4  = tid & 7;       // direct: float4 index (k = f4*4)
    const int t_n   = tid & 127;     // trans: LDS row (tile col of source)
    const int t_kh  = tid >> 7;      // trans: k-group parity

    f32x4 acc[4][4] = {};

    for (int k0 = 0; k0 < K; k0 += 32) {
        // ---------- stage A ----------
        if (A_TRANS) {
            #pragma unroll
            for (int p = 0; p < 4; ++p) {
                int kg = p * 2 + t_kh;
                float s0 = A[(size_t)(k0 + kg * 4 + 0) * M + m0 + t_n];
                float s1 = A[(size_t)(k0 + kg * 4 + 1) * M + m0 + t_n];
                float s2 = A[(size_t)(k0 + kg * 4 + 2) * M + m0 + t_n];
                float s3 = A[(size_t)(k0 + kg * 4 + 3) * M + m0 + t_n];
                unsigned h0,h1,h2,h3,l0,l1,l2,l3;
                bf16split(s0,h0,l0); bf16split(s1,h1,l1);
                bf16split(s2,h2,l2); bf16split(s3,h3,l3);
                int slot = kg ^ ((t_n >> 1) & 7);
                *(uint2*)&Ah[t_n * 32 + slot * 4] = make_uint2(h0 | (h1 << 16), h2 | (h3 << 16));
                *(uint2*)&Al[t_n * 32 + slot * 4] = make_uint2(l0 | (l1 << 16), l2 | (l3 << 16));
            }
        } else {
            #pragma unroll
            for (int it = 0; it < 4; ++it) {
                int r = it * 32 + d_row;
                float4 v = *(const float4*)&A[(size_t)(m0 + r) * K + k0 + d_f4 * 4];
                unsigned h0,h1,h2,h3,l0,l1,l2,l3;
                bf16split(v.x,h0,l0); bf16split(v.y,h1,l1);
                bf16split(v.z,h2,l2); bf16split(v.w,h3,l3);
                *(uint2*)&Ah[r * 32 + d_f4 * 4] = make_uint2(h0 | (h1 << 16), h2 | (h3 << 16));
                *(uint2*)&Al[r * 32 + d_f4 * 4] = make_uint2(l0 | (l1 << 16), l2 | (l3 << 16));
            }
        }
        // ---------- stage B ----------
        if (B_TRANS) {
            #pragma unroll
            for (int p = 0; p < 4; ++p) {
                int kg = p * 2 + t_kh;
                float s0 = Bm[(size_t)(k0 + kg * 4 + 0) * N + n0 + t_n];
                float s1 = Bm[(size_t)(k0 + kg * 4 + 1) * N + n0 + t_n];
                float s2 = Bm[(size_t)(k0 + kg * 4 + 2) * N + n0 + t_n];
                float s3 = Bm[(size_t)(k0 + kg * 4 + 3) * N + n0 + t_n];
                unsigned h0,h1,h2,h3,l0,l1,l2,l3;
                bf16split(s0,h0,l0); bf16split(s1,h1,l1);
                bf16split(s2,h2,l2); bf16split(s3,h3,l3);
                int slot = kg ^ ((t_n >> 1) & 7);
                *(uint2*)&Bh[t_n * 32 + slot * 4] = make_uint2(h0 | (h1 << 16), h2 | (h3 << 16));
                *(uint2*)&Bl[t_n * 32 + slot * 4] = make_uint2(l0 | (l1 << 16), l2 | (l3 << 16));
            }
        } else {
            #pragma unroll
            for (int it = 0; it < 4; ++it) {
                int r = it * 32 + d_row;
                float4 v = *(const float4*)&Bm[(size_t)(n0 + r) * K + k0 + d_f4 * 4];
                unsigned h0,h1,h2,h3,l0,l1,l2,l3;
                bf16split(v.x,h0,l0); bf16split(v.y,h1,l1);
                bf16split(v.z,h2,l2); bf16split(v.w,h3,l3);
                *(uint2*)&Bh[r * 32 + d_f4 * 4] = make_uint2(h0 | (h1 << 16), h2 | (h3 << 16));
                *(uint2*)&Bl[r * 32 + d_f4 * 4] = make_uint2(l0 | (l1 << 16), l2 | (l3 << 16));
            }
        }
        __syncthreads();

        // ---------- fragment loads ----------
        short8 ah[4], al[4], bh[4], bl[4];
        #pragma unroll
        for (int mi = 0; mi < 4; ++mi) {
            int r = wm * 64 + mi * 16 + r15;
            if (A_TRANS) {
                int s0 = (2 * q)     ^ ((r >> 1) & 7);
                int s1 = (2 * q + 1) ^ ((r >> 1) & 7);
                FragU f;
                f.u2[0] = *(uint2*)&Ah[r * 32 + s0 * 4];
                f.u2[1] = *(uint2*)&Ah[r * 32 + s1 * 4];
                ah[mi] = f.v;
                f.u2[0] = *(uint2*)&Al[r * 32 + s0 * 4];
                f.u2[1] = *(uint2*)&Al[r * 32 + s1 * 4];
                al[mi] = f.v;
            } else {
                ah[mi] = *(short8*)&Ah[r * 32 + q * 8];
                al[mi] = *(short8*)&Al[r * 32 + q * 8];
            }
        }
        #pragma unroll
        for (int ni = 0; ni < 4; ++ni) {
            int r = wn * 64 + ni * 16 + r15;
            if (B_TRANS) {
                int s0 = (2 * q)     ^ ((r >> 1) & 7);
                int s1 = (2 * q + 1) ^ ((r >> 1) & 7);
                FragU f;
                f.u2[0] = *(uint2*)&Bh[r * 32 + s0 * 4];
                f.u2[1] = *(uint2*)&Bh[r * 32 + s1 * 4];
                bh[ni] = f.v;
                f.u2[0] = *(uint2*)&Bl[r * 32 + s0 * 4];
                f.u2[1] = *(uint2*)&Bl[r * 32 + s1 * 4];
                bl[ni] = f.v;
            } else {
                bh[ni] = *(short8*)&Bh[r * 32 + q * 8];
                bl[ni] = *(short8*)&Bl[r * 32 + q * 8];
            }
        }
        // ---------- MFMA (bf16x3) ----------
        #pragma unroll
        for (int mi = 0; mi < 4; ++mi)
            #pragma unroll
            for (int ni = 0; ni < 4; ++ni) {
                acc[mi][ni] = __builtin_amdgcn_mfma_f32_16x16x32_bf16(ah[mi], bh[ni], acc[mi][ni], 0, 0, 0);
                acc[mi][ni] = __builtin_amdgcn_mfma_f32_16x16x32_bf16(ah[mi], bl[ni], acc[mi][ni], 0, 0, 0);
                acc[mi][ni] = __builtin_amdgcn_mfma_f32_16x16x32_bf16(al[mi], bh[ni], acc[mi][ni], 0, 0, 0);
            }
        __syncthreads();
    }

    // ---------- epilogue: gelu(acc + bias) ----------
    #pragma unroll
    for (int mi = 0; mi < 4; ++mi) {
        int gr0 = m0 + wm * 64 + mi * 16 + q * 4;
        #pragma unroll
        for (int ni = 0; ni < 4; ++ni) {
            int gc = n0 + wn * 64 + ni * 16 + r15;
            #pragma unroll
            for (int j = 0; j < 4; ++j) {
                int gr = gr0 + j;
                float b = BIAS_ROW ? bias[gr] : bias[gc];
                out[(size_t)gr * N + gc] = gelu_exact(acc[mi][ni][j] + b);
            }
        }
    }
}

// One block per (window b2, head h). T is the transposed gelu(qkv) tensor
// (3C x NTOK) flattened; q/k/v fragments are contiguous slices of it.
__global__ __launch_bounds__(256)
void attn_kernel(const float* __restrict__ T, const float* __restrict__ bias_table,
                 float* __restrict__ out) {
    const int b2 = blockIdx.x;
    const int h  = blockIdx.y;
    const size_t base = (size_t)b2 * 18816 + (size_t)h * 1568;

    __shared__ float q [SEQ][HD + 1];
    __shared__ float kk[SEQ][HD + 1];
    __shared__ float vv[SEQ][HD + 1];
    __shared__ float sc[SEQ][SEQ + 1];

    const int tid = threadIdx.x;
    for (int i = tid; i < SEQ * HD; i += 256) {
        int s = i / HD, d = i % HD;
        q [s][d] = T[base + i];
        kk[s][d] = T[QL + base + i];
        vv[s][d] = T[2 * QL + base + i];
    }
    __syncthreads();

    for (int i = tid; i < SEQ * SEQ; i += 256) {
        int s = i / SEQ, t = i % SEQ;
        float acc = 0.f;
        #pragma unroll
        for (int d = 0; d < HD; ++d) acc += q[s][d] * kk[t][d];
        int rel = 13 * ((t % 7) - (s % 7) + (t / 7) - (s / 7) + 12);
        sc[s][t] = acc + bias_table[rel * NHEADS + h];
    }
    __syncthreads();

    if (tid < SEQ) {
        float mx = -1e30f;
        #pragma unroll
        for (int t = 0; t < SEQ; ++t) mx = fmaxf(mx, sc[tid][t]);
        float sum = 0.f;
        #pragma unroll
        for (int t = 0; t < SEQ; ++t) { float e = __expf(sc[tid][t] - mx); sc[tid][t] = e; sum += e; }
        float inv = 1.0f / sum;
        #pragma unroll
        for (int t = 0; t < SEQ; ++t) sc[tid][t] *= inv;
    }
    __syncthreads();

    for (int i = tid; i < SEQ * HD; i += 256) {
        int s = i / HD, d = i % HD;
        float acc = 0.f;
        #pragma unroll
        for (int t = 0; t < SEQ; ++t) acc += sc[s][t] * vv[t][d];
        int n = b2 * SEQ + s;
        out[(size_t)n * CDIM + h * HD + d] = acc;
    }
}

extern "C" void kernel_launch(void* const* d_in, const int* in_sizes, int n_in,
                              void* d_out, int out_size, void* d_ws, size_t ws_size,
                              hipStream_t stream) {
    const float* x          = (const float*)d_in[0];
    const float* w_qkv      = (const float*)d_in[1];
    const float* b_qkv      = (const float*)d_in[2];
    const float* bias_table = (const float*)d_in[3];
    const float* w_out      = (const float*)d_in[4];
    const float* b_out      = (const float*)d_in[5];
    float* out = (float*)d_out;
    float* T   = (float*)d_ws;   // 3C x NTOK fp32 = 924.8 MB (known-safe)
    float* Y1  = (float*)d_ws;   // reuses T space after attention

    // 1) T = gelu(w_qkv^T @ x^T + b_qkv)  -> (1152 x 200704), computed transposed
    gemm_b3<true, false, true><<<dim3(NH3 / 128, NTOK / 128), 256, 0, stream>>>(
        w_qkv, x, b_qkv, T, NH3, NTOK, CDIM);

    // 2) attention -> Y0 staged in d_out (NTOK x C)
    attn_kernel<<<dim3(4096, NHEADS), 256, 0, stream>>>(T, bias_table, out);

    // 3) Y1 = gelu(Y0 @ w_out + b_out)   (T is dead; reuse ws)
    gemm_b3<false, true, false><<<dim3(CDIM / 128, NTOK / 128), 256, 0, stream>>>(
        out, w_out, b_out, Y1, NTOK, CDIM, CDIM);

    // 4) out = gelu(Y1 @ w_out + b_out)
    gemm_b3<false, true, false><<<dim3(CDIM / 128, NTOK / 128), 256, 0, stream>>>(
        Y1, w_out, b_out, out, NTOK, CDIM, CDIM);
}

// Round 3
// 1798.924 us; speedup vs baseline: 3.7914x; 1.4067x over previous
//
#include <hip/hip_runtime.h>
#include <math.h>

#define NTOK 200704          // B*S = 4096*49
#define CDIM 384
#define NH3 1152             // 3*C
#define NHEADS 12
#define HD 32
#define SEQ 49
#define QL 77070336ULL       // CDIM*NTOK (one third of T)

typedef __attribute__((ext_vector_type(8))) short short8;
typedef __attribute__((ext_vector_type(4))) float f32x4;

__device__ __forceinline__ float gelu_exact(float x) {
    return 0.5f * x * (1.0f + erff(x * 0.70710678118654752f));
}

// round-to-nearest-even bf16 of x, as fp32 bit pattern (low 16 zero)
__device__ __forceinline__ unsigned bf16rn_bits(float x) {
    unsigned u = __float_as_uint(x);
    return (u + 0x7fffu + ((u >> 16) & 1u)) & 0xffff0000u;
}
__device__ __forceinline__ void bf16split(float x, unsigned &h, unsigned &l) {
    unsigned hu = bf16rn_bits(x);
    h = hu >> 16;
    float r = x - __uint_as_float(hu);
    l = bf16rn_bits(r) >> 16;
}

__device__ __forceinline__ void gl_lds16(const void* g, void* l) {
    __builtin_amdgcn_global_load_lds((const __attribute__((address_space(1))) void*)g,
                                     (__attribute__((address_space(3))) void*)l, 16, 0, 0);
}

// ---------------------------------------------------------------------------
// prep: w (Kdim x Mdim row-major fp32) -> hi/lo bf16 in granule layout
// [koct][m][8]: granule g = koct*Mdim + m holds w[koct*8+j][m], j=0..7.
// ---------------------------------------------------------------------------
__global__ __launch_bounds__(256)
void prep_w(const float* __restrict__ w, unsigned short* __restrict__ hi,
            unsigned short* __restrict__ lo, int Mdim, int Kdim) {
    int idx = blockIdx.x * 256 + threadIdx.x;
    int total = Mdim * (Kdim >> 3);
    if (idx >= total) return;
    int koct = idx / Mdim, m = idx - koct * Mdim;
    unsigned short h8[8], l8[8];
    #pragma unroll
    for (int j = 0; j < 8; ++j) {
        unsigned h, l;
        bf16split(w[(size_t)(koct * 8 + j) * Mdim + m], h, l);
        h8[j] = (unsigned short)h; l8[j] = (unsigned short)l;
    }
    size_t o = (size_t)idx * 8;
    *(short8*)&hi[o] = *(short8*)h8;
    *(short8*)&lo[o] = *(short8*)l8;
}

// ---------------------------------------------------------------------------
// bf16x3 GEMM: out[m][n] = gelu(sum_k A[m][k]*B[n][k] + bias)
// A_PRE: A comes as pre-split bf16 granule arrays (Aph/Apl), staged via
//        global_load_lds. Else A is fp32 M x K row-major, inline split.
// Same for B. LDS layout per operand: [q][128][8] shorts (q = k-octet in step).
// Tile 128x128, BK=32, 256 threads (4 waves 2x2 of 64x64).
// ---------------------------------------------------------------------------
template<bool A_PRE, bool B_PRE, bool BIAS_ROW>
__global__ __launch_bounds__(256, 2)
void gemm_b3(const float* __restrict__ Af, const unsigned short* __restrict__ Aph,
             const unsigned short* __restrict__ Apl,
             const float* __restrict__ Bf, const unsigned short* __restrict__ Bph,
             const unsigned short* __restrict__ Bpl,
             const float* __restrict__ bias, float* __restrict__ out,
             int M, int N, int K) {
    __shared__ unsigned short Ah[4][128][8], Al[4][128][8];
    __shared__ unsigned short Bh[4][128][8], Bl[4][128][8];

    const int tid = threadIdx.x;
    const int n0 = blockIdx.x * 128;
    const int m0 = blockIdx.y * 128;

    const int wid = tid >> 6, lane = tid & 63;
    const int wm = wid >> 1, wn = wid & 1;
    const int r15 = lane & 15, q = lane >> 4;

    // fp32 staging map: 8 threads cover one row's 32-float k-slice
    const int f_r  = tid >> 3;       // 0..31 (row within 32-row group)
    const int f_f4 = tid & 7;        // float4 index; granule qq=f4>>1, half=(f4&1)
    const int f_qq = f_f4 >> 1, f_half = (f_f4 & 1) * 8;  // byte offset within granule

    f32x4 acc[4][4] = {};

    for (int k0 = 0; k0 < K; k0 += 32) {
        const int kb = k0 >> 3;   // k-octet base
        // ---------- stage A ----------
        if (A_PRE) {
            #pragma unroll
            for (int it = 0; it < 2; ++it) {
                int g = it * 256 + tid;             // granule 0..511
                int qq = g >> 7, r = g & 127;
                size_t src = ((size_t)(kb + qq) * M + m0 + r) * 8;
                gl_lds16(&Aph[src], &Ah[0][0][0] + (size_t)g * 8);
                gl_lds16(&Apl[src], &Al[0][0][0] + (size_t)g * 8);
            }
        } else {
            #pragma unroll
            for (int it = 0; it < 4; ++it) {
                int r = it * 32 + f_r;
                float4 v = *(const float4*)&Af[(size_t)(m0 + r) * K + k0 + f_f4 * 4];
                unsigned h0,h1,h2,h3,l0,l1,l2,l3;
                bf16split(v.x,h0,l0); bf16split(v.y,h1,l1);
                bf16split(v.z,h2,l2); bf16split(v.w,h3,l3);
                *(uint2*)((char*)&Ah[f_qq][r][0] + f_half) = make_uint2(h0|(h1<<16), h2|(h3<<16));
                *(uint2*)((char*)&Al[f_qq][r][0] + f_half) = make_uint2(l0|(l1<<16), l2|(l3<<16));
            }
        }
        // ---------- stage B ----------
        if (B_PRE) {
            #pragma unroll
            for (int it = 0; it < 2; ++it) {
                int g = it * 256 + tid;
                int qq = g >> 7, r = g & 127;
                size_t src = ((size_t)(kb + qq) * N + n0 + r) * 8;
                gl_lds16(&Bph[src], &Bh[0][0][0] + (size_t)g * 8);
                gl_lds16(&Bpl[src], &Bl[0][0][0] + (size_t)g * 8);
            }
        } else {
            #pragma unroll
            for (int it = 0; it < 4; ++it) {
                int r = it * 32 + f_r;
                float4 v = *(const float4*)&Bf[(size_t)(n0 + r) * K + k0 + f_f4 * 4];
                unsigned h0,h1,h2,h3,l0,l1,l2,l3;
                bf16split(v.x,h0,l0); bf16split(v.y,h1,l1);
                bf16split(v.z,h2,l2); bf16split(v.w,h3,l3);
                *(uint2*)((char*)&Bh[f_qq][r][0] + f_half) = make_uint2(h0|(h1<<16), h2|(h3<<16));
                *(uint2*)((char*)&Bl[f_qq][r][0] + f_half) = make_uint2(l0|(l1<<16), l2|(l3<<16));
            }
        }
        __syncthreads();

        // ---------- fragment loads (conflict-free: granule col = row&7) ----------
        short8 ah[4], al[4], bh[4], bl[4];
        #pragma unroll
        for (int mi = 0; mi < 4; ++mi) {
            int r = wm * 64 + mi * 16 + r15;
            ah[mi] = *(short8*)&Ah[q][r][0];
            al[mi] = *(short8*)&Al[q][r][0];
        }
        #pragma unroll
        for (int ni = 0; ni < 4; ++ni) {
            int r = wn * 64 + ni * 16 + r15;
            bh[ni] = *(short8*)&Bh[q][r][0];
            bl[ni] = *(short8*)&Bl[q][r][0];
        }
        // ---------- MFMA (bf16x3) ----------
        #pragma unroll
        for (int mi = 0; mi < 4; ++mi)
            #pragma unroll
            for (int ni = 0; ni < 4; ++ni) {
                acc[mi][ni] = __builtin_amdgcn_mfma_f32_16x16x32_bf16(ah[mi], bh[ni], acc[mi][ni], 0, 0, 0);
                acc[mi][ni] = __builtin_amdgcn_mfma_f32_16x16x32_bf16(ah[mi], bl[ni], acc[mi][ni], 0, 0, 0);
                acc[mi][ni] = __builtin_amdgcn_mfma_f32_16x16x32_bf16(al[mi], bh[ni], acc[mi][ni], 0, 0, 0);
            }
        __syncthreads();
    }

    // ---------- epilogue ----------
    #pragma unroll
    for (int mi = 0; mi < 4; ++mi) {
        int gr0 = m0 + wm * 64 + mi * 16 + q * 4;
        #pragma unroll
        for (int ni = 0; ni < 4; ++ni) {
            int gc = n0 + wn * 64 + ni * 16 + r15;
            #pragma unroll
            for (int j = 0; j < 4; ++j) {
                int gr = gr0 + j;
                float b = BIAS_ROW ? bias[gr] : bias[gc];
                out[(size_t)gr * N + gc] = gelu_exact(acc[mi][ni][j] + b);
            }
        }
    }
}

// ---------------------------------------------------------------------------
// attention: one WAVE per (window, head). Lane s owns score row s in regs;
// k/v in per-wave LDS (broadcast reads); softmax lane-local; no syncthreads.
// ---------------------------------------------------------------------------
__global__ __launch_bounds__(256)
void attn_kernel(const float* __restrict__ T, const float* __restrict__ bias_table,
                 float* __restrict__ out) {
    __shared__ float kv[4][2][SEQ * HD];   // [wave][k|v][1568] = 50176 B
    const int tid = threadIdx.x, wid = tid >> 6, lane = tid & 63;
    const int pidx = blockIdx.x * 4 + wid;
    const int b2 = pidx / NHEADS, h = pidx - b2 * NHEADS;
    const size_t base = (size_t)b2 * 18816 + (size_t)h * 1568;

    float* kk = kv[wid][0];
    float* vv = kv[wid][1];

    // stage k, v (coalesced float4, lane-strided)
    for (int i = lane; i < SEQ * HD / 4; i += 64) {
        *(float4*)&kk[i * 4] = *(const float4*)&T[QL + base + i * 4];
        *(float4*)&vv[i * 4] = *(const float4*)&T[2 * QL + base + i * 4];
    }

    const bool act = lane < SEQ;
    const int s = act ? lane : 0;

    // q row in registers
    float qr[HD];
    #pragma unroll
    for (int g = 0; g < 8; ++g) {
        float4 t4 = *(const float4*)&T[base + (size_t)s * HD + g * 4];
        qr[g*4+0] = t4.x; qr[g*4+1] = t4.y; qr[g*4+2] = t4.z; qr[g*4+3] = t4.w;
    }
    // bias: rel(s,t) = c_s + 13*(t%7 + t/7); 13 distinct values per lane
    const int cs = 13 * (12 - s % 7 - s / 7);
    float br[13];
    #pragma unroll
    for (int u = 0; u < 13; ++u)
        br[u] = bias_table[(size_t)(cs + 13 * u) * NHEADS + h];

    // scores (LDS broadcast reads)
    float p[SEQ];
    #pragma unroll
    for (int t = 0; t < SEQ; ++t) {
        float a = 0.f;
        #pragma unroll
        for (int g = 0; g < 8; ++g) {
            float4 k4 = *(const float4*)&kk[t * HD + g * 4];
            a += qr[g*4+0]*k4.x + qr[g*4+1]*k4.y + qr[g*4+2]*k4.z + qr[g*4+3]*k4.w;
        }
        p[t] = a + br[t % 7 + t / 7];
    }
    // lane-local softmax
    float mx = p[0];
    #pragma unroll
    for (int t = 1; t < SEQ; ++t) mx = fmaxf(mx, p[t]);
    float sum = 0.f;
    #pragma unroll
    for (int t = 0; t < SEQ; ++t) { p[t] = __expf(p[t] - mx); sum += p[t]; }
    const float inv = 1.0f / sum;

    // PV (broadcast reads)
    float o[HD] = {};
    #pragma unroll
    for (int t = 0; t < SEQ; ++t) {
        #pragma unroll
        for (int g = 0; g < 8; ++g) {
            float4 v4 = *(const float4*)&vv[t * HD + g * 4];
            o[g*4+0] += p[t]*v4.x; o[g*4+1] += p[t]*v4.y;
            o[g*4+2] += p[t]*v4.z; o[g*4+3] += p[t]*v4.w;
        }
    }
    if (act) {
        size_t o0 = ((size_t)b2 * SEQ + s) * CDIM + (size_t)h * HD;
        #pragma unroll
        for (int g = 0; g < 8; ++g)
            *(float4*)&out[o0 + g * 4] =
                make_float4(o[g*4+0]*inv, o[g*4+1]*inv, o[g*4+2]*inv, o[g*4+3]*inv);
    }
}

extern "C" void kernel_launch(void* const* d_in, const int* in_sizes, int n_in,
                              void* d_out, int out_size, void* d_ws, size_t ws_size,
                              hipStream_t stream) {
    const float* x          = (const float*)d_in[0];
    const float* w_qkv      = (const float*)d_in[1];
    const float* b_qkv      = (const float*)d_in[2];
    const float* bias_table = (const float*)d_in[3];
    const float* w_out      = (const float*)d_in[4];
    const float* b_out      = (const float*)d_in[5];
    float* out = (float*)d_out;
    float* T   = (float*)d_ws;                        // 3*QL floats (925 MB)
    float* Y1  = (float*)d_ws;                        // aliases first third after attn

    // weight scratch: wqkvT in d_out (free until attention writes Y0);
    // woutT in T's second third (dead after attention reads k).
    unsigned short* wqkv_hi = (unsigned short*)d_out;
    unsigned short* wqkv_lo = wqkv_hi + (size_t)NH3 * CDIM;
    unsigned short* wout_hi = (unsigned short*)(T + QL);
    unsigned short* wout_lo = wout_hi + (size_t)CDIM * CDIM;

    // 0) prep wqkv^T -> granule bf16 hi/lo
    prep_w<<<dim3((NH3 * (CDIM / 8) + 255) / 256), 256, 0, stream>>>(
        w_qkv, wqkv_hi, wqkv_lo, NH3, CDIM);

    // 1) T = gelu(w_qkv^T @ x^T + b_qkv)  (M=1152 channels, N=200704 tokens)
    gemm_b3<true, false, true><<<dim3(NTOK / 128, NH3 / 128), 256, 0, stream>>>(
        nullptr, wqkv_hi, wqkv_lo, x, nullptr, nullptr, b_qkv, T, NH3, NTOK, CDIM);

    // 2) attention -> Y0 in d_out (NTOK x C)
    attn_kernel<<<dim3(4096 * NHEADS / 4), 256, 0, stream>>>(T, bias_table, out);

    // 2b) prep wout^T (after attn: T's second third is dead)
    prep_w<<<dim3((CDIM * (CDIM / 8) + 255) / 256), 256, 0, stream>>>(
        w_out, wout_hi, wout_lo, CDIM, CDIM);

    // 3) Y1 = gelu(Y0 @ w_out + b_out)  (M=200704, N=384)
    gemm_b3<false, true, false><<<dim3(CDIM / 128, NTOK / 128), 256, 0, stream>>>(
        out, nullptr, nullptr, nullptr, wout_hi, wout_lo, b_out, Y1, NTOK, CDIM, CDIM);

    // 4) out = gelu(Y1 @ w_out + b_out)
    gemm_b3<false, true, false><<<dim3(CDIM / 128, NTOK / 128), 256, 0, stream>>>(
        Y1, nullptr, nullptr, nullptr, wout_hi, wout_lo, b_out, out, NTOK, CDIM, CDIM);
}

// Round 4
// 1585.847 us; speedup vs baseline: 4.3008x; 1.1344x over previous
//
#include <hip/hip_runtime.h>
#include <math.h>

#define NTOK 200704          // B*S = 4096*49
#define CDIM 384
#define NH3  1152            // 3*C
#define NHEADS 12
#define HD   32
#define SEQ  49
#define QL   77070336ULL     // CDIM*NTOK (one third of T)

typedef __attribute__((ext_vector_type(8))) short short8;
typedef __attribute__((ext_vector_type(4))) float f32x4;

__device__ __forceinline__ float gelu_exact(float x) {
    return 0.5f * x * (1.0f + erff(x * 0.70710678118654752f));
}
// round-to-nearest-even bf16 of x, as fp32 bit pattern (low 16 zero)
__device__ __forceinline__ unsigned bf16rn_bits(float x) {
    unsigned u = __float_as_uint(x);
    return (u + 0x7fffu + ((u >> 16) & 1u)) & 0xffff0000u;
}
// packed split: hi bf16 in top16, lo bf16 in low16 (same 4 bytes as the fp32)
__device__ __forceinline__ unsigned packsplit(float x) {
    unsigned hb = bf16rn_bits(x);
    float r = x - __uint_as_float(hb);
    unsigned lb = bf16rn_bits(r);
    return hb | (lb >> 16);
}
__device__ __forceinline__ void gl_lds16(const void* g, void* l) {
    __builtin_amdgcn_global_load_lds((const __attribute__((address_space(1))) void*)g,
                                     (__attribute__((address_space(3))) void*)l, 16, 0, 0);
}
union F8 { short8 v; unsigned u[4]; };
// 8 packed words -> hi short8 + lo short8 (element j ascending)
__device__ __forceinline__ void unpack8(uint4 a, uint4 b, short8 &h, short8 &l) {
    F8 H, L;
    H.u[0] = __builtin_amdgcn_perm(a.y, a.x, 0x07060302u);
    H.u[1] = __builtin_amdgcn_perm(a.w, a.z, 0x07060302u);
    H.u[2] = __builtin_amdgcn_perm(b.y, b.x, 0x07060302u);
    H.u[3] = __builtin_amdgcn_perm(b.w, b.z, 0x07060302u);
    L.u[0] = __builtin_amdgcn_perm(a.y, a.x, 0x05040100u);
    L.u[1] = __builtin_amdgcn_perm(a.w, a.z, 0x05040100u);
    L.u[2] = __builtin_amdgcn_perm(b.y, b.x, 0x05040100u);
    L.u[3] = __builtin_amdgcn_perm(b.w, b.z, 0x05040100u);
    h = H.v; l = L.v;
}

// ---------------------------------------------------------------------------
// prep_w: w (Kdim x Mdim row-major fp32) -> hi/lo bf16 granules [koct][m][8]
// ---------------------------------------------------------------------------
__global__ __launch_bounds__(256)
void prep_w(const float* __restrict__ w, unsigned short* __restrict__ hi,
            unsigned short* __restrict__ lo, int Mdim, int Kdim) {
    int idx = blockIdx.x * 256 + threadIdx.x;
    int total = Mdim * (Kdim >> 3);
    if (idx >= total) return;
    int koct = idx / Mdim, m = idx - koct * Mdim;
    unsigned short h8[8], l8[8];
    #pragma unroll
    for (int j = 0; j < 8; ++j) {
        float v = w[(size_t)(koct * 8 + j) * Mdim + m];
        unsigned hb = bf16rn_bits(v);
        h8[j] = (unsigned short)(hb >> 16);
        l8[j] = (unsigned short)(bf16rn_bits(v - __uint_as_float(hb)) >> 16);
    }
    size_t o = (size_t)idx * 8;
    *(short8*)&hi[o] = *(short8*)h8;
    *(short8*)&lo[o] = *(short8*)l8;
}

// prep_x: fp32 row-major -> packed-split u32, same layout
__global__ __launch_bounds__(256)
void prep_x(const float* __restrict__ x, unsigned* __restrict__ xp, int total8) {
    int idx = blockIdx.x * 256 + threadIdx.x;
    if (idx >= total8) return;
    size_t e = (size_t)idx * 8;
    float4 v0 = *(const float4*)&x[e];
    float4 v1 = *(const float4*)&x[e + 4];
    *(uint4*)&xp[e]     = make_uint4(packsplit(v0.x), packsplit(v0.y), packsplit(v0.z), packsplit(v0.w));
    *(uint4*)&xp[e + 4] = make_uint4(packsplit(v1.x), packsplit(v1.y), packsplit(v1.z), packsplit(v1.w));
}

// ---------------------------------------------------------------------------
// bf16x3 GEMM: out[m][n] = gelu(sum_k A[m][k]*B[n][k] + bias)
// MODE 0: fp32 source (rows x K), inline split into granule LDS
// MODE 1: pre-split granule arrays (hi/lo u16), staged via global_load_lds
// MODE 2: packed-u32 source, staged via global_load_lds w/ swizzled src, v_perm unpack
// Tile 128x128, BK=32, 256 threads (2x2 waves of 64x64).
// ---------------------------------------------------------------------------
template<int AMODE, int BMODE, bool BIAS_ROW, bool OUTF>
__global__ __launch_bounds__(256, 2)
void gemm_b3(const float* __restrict__ Af,
             const unsigned short* __restrict__ Agh, const unsigned short* __restrict__ Agl,
             const unsigned* __restrict__ Ap,
             const float* __restrict__ Bf,
             const unsigned short* __restrict__ Bgh, const unsigned short* __restrict__ Bgl,
             const unsigned* __restrict__ Bp,
             const float* __restrict__ bias, float* __restrict__ outF,
             unsigned* __restrict__ outP,
             int M, int N, int K, int nMt, int cpx) {
    __shared__ char smA[16384];
    __shared__ char smB[16384];
    const int tid = threadIdx.x;
    int m0, n0;
    if (cpx > 0) {  // XCD-chunked 1D grid: consecutive wg share the B (token) tile
        int wg = (blockIdx.x & 7) * cpx + (blockIdx.x >> 3);
        m0 = (wg % nMt) * 128;
        n0 = (wg / nMt) * 128;
    } else {
        n0 = blockIdx.x * 128;
        m0 = blockIdx.y * 128;
    }
    const int wid = tid >> 6, lane = tid & 63;
    const int wm = wid >> 1, wn = wid & 1;
    const int r15 = lane & 15, q = lane >> 4;
    const int f_r = tid >> 3, f_f4 = tid & 7;
    const int f_qq = f_f4 >> 1, f_half = (f_f4 & 1) * 8;

    unsigned short* AhT = (unsigned short*)smA;            // [4][128][8]
    unsigned short* AlT = (unsigned short*)(smA + 8192);
    unsigned*       ApT = (unsigned*)smA;                  // [128][32] swizzled
    unsigned short* BhT = (unsigned short*)smB;
    unsigned short* BlT = (unsigned short*)(smB + 8192);
    unsigned*       BpT = (unsigned*)smB;

    f32x4 acc[4][4] = {};

    for (int k0 = 0; k0 < K; k0 += 32) {
        const int kb = k0 >> 3;
        // ---------------- stage A ----------------
        if constexpr (AMODE == 1) {
            #pragma unroll
            for (int it = 0; it < 2; ++it) {
                int g = it * 256 + tid;
                int qq = g >> 7, r = g & 127;
                size_t src = ((size_t)(kb + qq) * M + m0 + r) * 8;
                gl_lds16(Agh + src, smA + g * 16);
                gl_lds16(Agl + src, smA + 8192 + g * 16);
            }
        } else if constexpr (AMODE == 2) {
            #pragma unroll
            for (int it = 0; it < 4; ++it) {
                int row = it * 32 + (tid >> 3);
                int slot = (tid & 7) ^ (row & 7);
                gl_lds16(Ap + (size_t)(m0 + row) * K + k0 + slot * 4,
                         smA + (size_t)(it * 256 + tid) * 16);
            }
        }
        // ---------------- stage B ----------------
        if constexpr (BMODE == 1) {
            #pragma unroll
            for (int it = 0; it < 2; ++it) {
                int g = it * 256 + tid;
                int qq = g >> 7, r = g & 127;
                size_t src = ((size_t)(kb + qq) * N + n0 + r) * 8;
                gl_lds16(Bgh + src, smB + g * 16);
                gl_lds16(Bgl + src, smB + 8192 + g * 16);
            }
        } else if constexpr (BMODE == 2) {
            #pragma unroll
            for (int it = 0; it < 4; ++it) {
                int row = it * 32 + (tid >> 3);
                int slot = (tid & 7) ^ (row & 7);
                gl_lds16(Bp + (size_t)(n0 + row) * K + k0 + slot * 4,
                         smB + (size_t)(it * 256 + tid) * 16);
            }
        } else {  // fp32 inline split
            #pragma unroll
            for (int it = 0; it < 4; ++it) {
                int r = it * 32 + f_r;
                float4 v = *(const float4*)&Bf[(size_t)(n0 + r) * K + k0 + f_f4 * 4];
                unsigned hb0 = bf16rn_bits(v.x), hb1 = bf16rn_bits(v.y);
                unsigned hb2 = bf16rn_bits(v.z), hb3 = bf16rn_bits(v.w);
                unsigned l0 = bf16rn_bits(v.x - __uint_as_float(hb0)) >> 16;
                unsigned l1 = bf16rn_bits(v.y - __uint_as_float(hb1)) >> 16;
                unsigned l2 = bf16rn_bits(v.z - __uint_as_float(hb2)) >> 16;
                unsigned l3 = bf16rn_bits(v.w - __uint_as_float(hb3)) >> 16;
                unsigned h0 = hb0 >> 16, h1 = hb1 >> 16, h2 = hb2 >> 16, h3 = hb3 >> 16;
                *(uint2*)((char*)(BhT + (f_qq * 128 + r) * 8) + f_half) =
                    make_uint2(h0 | (h1 << 16), h2 | (h3 << 16));
                *(uint2*)((char*)(BlT + (f_qq * 128 + r) * 8) + f_half) =
                    make_uint2(l0 | (l1 << 16), l2 | (l3 << 16));
            }
        }
        __syncthreads();

        // ---------------- fragment loads ----------------
        short8 ah[4], al[4], bh[4], bl[4];
        #pragma unroll
        for (int mi = 0; mi < 4; ++mi) {
            int r = wm * 64 + mi * 16 + r15;
            if constexpr (AMODE == 2) {
                int s0 = (2 * q) ^ (r & 7), s1 = s0 ^ 1;
                const unsigned* base = ApT + r * 32;
                uint4 a = *(const uint4*)(base + s0 * 4);
                uint4 b = *(const uint4*)(base + s1 * 4);
                unpack8(a, b, ah[mi], al[mi]);
            } else {
                ah[mi] = *(const short8*)(AhT + (q * 128 + r) * 8);
                al[mi] = *(const short8*)(AlT + (q * 128 + r) * 8);
            }
        }
        #pragma unroll
        for (int ni = 0; ni < 4; ++ni) {
            int r = wn * 64 + ni * 16 + r15;
            if constexpr (BMODE == 2) {
                int s0 = (2 * q) ^ (r & 7), s1 = s0 ^ 1;
                const unsigned* base = BpT + r * 32;
                uint4 a = *(const uint4*)(base + s0 * 4);
                uint4 b = *(const uint4*)(base + s1 * 4);
                unpack8(a, b, bh[ni], bl[ni]);
            } else {
                bh[ni] = *(const short8*)(BhT + (q * 128 + r) * 8);
                bl[ni] = *(const short8*)(BlT + (q * 128 + r) * 8);
            }
        }
        // ---------------- MFMA (bf16x3) ----------------
        #pragma unroll
        for (int mi = 0; mi < 4; ++mi)
            #pragma unroll
            for (int ni = 0; ni < 4; ++ni) {
                acc[mi][ni] = __builtin_amdgcn_mfma_f32_16x16x32_bf16(ah[mi], bh[ni], acc[mi][ni], 0, 0, 0);
                acc[mi][ni] = __builtin_amdgcn_mfma_f32_16x16x32_bf16(ah[mi], bl[ni], acc[mi][ni], 0, 0, 0);
                acc[mi][ni] = __builtin_amdgcn_mfma_f32_16x16x32_bf16(al[mi], bh[ni], acc[mi][ni], 0, 0, 0);
            }
        __syncthreads();
    }

    // ---------------- epilogue ----------------
    #pragma unroll
    for (int mi = 0; mi < 4; ++mi) {
        int gr0 = m0 + wm * 64 + mi * 16 + q * 4;
        #pragma unroll
        for (int ni = 0; ni < 4; ++ni) {
            int gc = n0 + wn * 64 + ni * 16 + r15;
            #pragma unroll
            for (int j = 0; j < 4; ++j) {
                int gr = gr0 + j;
                float b = BIAS_ROW ? bias[gr] : bias[gc];
                float v = gelu_exact(acc[mi][ni][j] + b);
                if constexpr (OUTF) outF[(size_t)gr * N + gc] = v;
                else                outP[(size_t)gr * N + gc] = packsplit(v);
            }
        }
    }
}

// ---------------------------------------------------------------------------
// MFMA attention: one wave per (window, head). T is packed hi|lo split.
// Per (b2,h): q/k/v tiles are contiguous [s][d] (the "scramble" is identity
// on flat addresses). S^T = mfma(K,Q) w/ bias in C; lane-group softmax;
// P normalized+split, routed via swizzled per-wave LDS into A-frags; V
// transposed per-wave into LDS for B-frags. All bf16x3.
// ---------------------------------------------------------------------------
__global__ __launch_bounds__(256, 2)
void attn_mfma(const unsigned* __restrict__ Tp, const float* __restrict__ bias_table,
               unsigned* __restrict__ Yp) {
    __shared__ unsigned short Vh[4][32][72];
    __shared__ unsigned short Vl[4][32][72];
    __shared__ unsigned PHs[4][16][36];
    __shared__ unsigned PLs[4][16][36];

    const int tid = threadIdx.x, wid = tid >> 6, lane = tid & 63;
    const int pidx = blockIdx.x * 4 + wid;
    const int b2 = pidx / NHEADS, h = pidx - b2 * NHEADS;
    const size_t qoff = (size_t)b2 * 18816 + (size_t)h * 1568;
    const int r15 = lane & 15, g = lane >> 4;

    // ---- stage V^T: [d][t] u16 hi/lo, t padded to 64 (clamped source) ----
    #pragma unroll
    for (int it = 0; it < 8; ++it) {
        int idx = it * 64 + lane;          // 0..511
        int t = idx >> 3, dq = idx & 7;
        int tc = t > 48 ? 48 : t;
        uint4 w = *(const uint4*)&Tp[2 * QL + qoff + (size_t)tc * HD + dq * 4];
        #pragma unroll
        for (int c = 0; c < 4; ++c) {
            unsigned pw = (c == 0) ? w.x : (c == 1) ? w.y : (c == 2) ? w.z : w.w;
            Vh[wid][dq * 4 + c][t] = (unsigned short)(pw >> 16);
            Vl[wid][dq * 4 + c][t] = (unsigned short)(pw & 0xffffu);
        }
    }
    __syncthreads();

    // ---- bias -> C init: rel(s,t) = 13*((t%7-s%7)+(t/7-s/7)+12) ----
    f32x4 S[4][4];
    int cS[4];
    #pragma unroll
    for (int st = 0; st < 4; ++st) {
        int s = st * 16 + r15; if (s > 48) s = 48;
        int sd = (s * 37) >> 8;               // s/7 for s<64
        cS[st] = 156 * (12 - (s - 6 * sd)) + h;
    }
    #pragma unroll
    for (int tt = 0; tt < 4; ++tt)
        #pragma unroll
        for (int r = 0; r < 4; ++r) {
            int t = tt * 16 + 4 * g + r; int tc2 = t > 48 ? 48 : t;
            int td = (tc2 * 37) >> 8;
            int at = 156 * (tc2 - 6 * td);
            #pragma unroll
            for (int st = 0; st < 4; ++st)
                S[tt][st][r] = bias_table[at + cS[st]];
        }

    // ---- Q fragments (B-operand): col s = l&15, k = d ----
    short8 qh[4], qlo[4];
    #pragma unroll
    for (int st = 0; st < 4; ++st) {
        int s = st * 16 + r15; if (s > 48) s = 48;
        const unsigned* p = Tp + qoff + (size_t)s * HD + g * 8;
        uint4 a = *(const uint4*)p;
        uint4 b = *(const uint4*)(p + 4);
        unpack8(a, b, qh[st], qlo[st]);
    }
    // ---- QK^T: S^T[t][s], K as A-operand (row t = l&15) ----
    #pragma unroll
    for (int tt = 0; tt < 4; ++tt) {
        int t = tt * 16 + r15; if (t > 48) t = 48;
        const unsigned* p = Tp + QL + qoff + (size_t)t * HD + g * 8;
        uint4 a = *(const uint4*)p;
        uint4 b = *(const uint4*)(p + 4);
        short8 kh, kl; unpack8(a, b, kh, kl);
        #pragma unroll
        for (int st = 0; st < 4; ++st) {
            S[tt][st] = __builtin_amdgcn_mfma_f32_16x16x32_bf16(kh, qh[st],  S[tt][st], 0, 0, 0);
            S[tt][st] = __builtin_amdgcn_mfma_f32_16x16x32_bf16(kh, qlo[st], S[tt][st], 0, 0, 0);
            S[tt][st] = __builtin_amdgcn_mfma_f32_16x16x32_bf16(kl, qh[st],  S[tt][st], 0, 0, 0);
        }
    }
    // ---- mask padded t (tile 3: t = 48+4g+r; only g==0,r==0 is real) ----
    #pragma unroll
    for (int st = 0; st < 4; ++st) {
        S[3][st][0] = (g == 0) ? S[3][st][0] : -1e30f;
        S[3][st][1] = -1e30f; S[3][st][2] = -1e30f; S[3][st][3] = -1e30f;
    }
    // ---- softmax per s (4-lane group reduce over g) ----
    float inv[4];
    #pragma unroll
    for (int st = 0; st < 4; ++st) {
        float mx = -1e30f;
        #pragma unroll
        for (int tt = 0; tt < 4; ++tt)
            #pragma unroll
            for (int r = 0; r < 4; ++r) mx = fmaxf(mx, S[tt][st][r]);
        mx = fmaxf(mx, __shfl_xor(mx, 16));
        mx = fmaxf(mx, __shfl_xor(mx, 32));
        float sm = 0.f;
        #pragma unroll
        for (int tt = 0; tt < 4; ++tt)
            #pragma unroll
            for (int r = 0; r < 4; ++r) {
                float e = __expf(S[tt][st][r] - mx);
                S[tt][st][r] = e; sm += e;
            }
        sm += __shfl_xor(sm, 16);
        sm += __shfl_xor(sm, 32);
        inv[st] = 1.0f / sm;
    }
    // ---- V fragments (B-operand, hoisted) ----
    short8 vfh[2][2], vfl[2][2];
    #pragma unroll
    for (int dt = 0; dt < 2; ++dt)
        #pragma unroll
        for (int kc = 0; kc < 2; ++kc) {
            int d = dt * 16 + r15;
            vfh[dt][kc] = *(const short8*)&Vh[wid][d][kc * 32 + g * 8];
            vfl[dt][kc] = *(const short8*)&Vl[wid][d][kc * 32 + g * 8];
        }
    // ---- per s-tile: P -> LDS (swizzled), PV, store ----
    for (int st = 0; st < 4; ++st) {
        #pragma unroll
        for (int tt = 0; tt < 4; ++tt)
            #pragma unroll
            for (int rp = 0; rp < 2; ++rp) {
                float p0 = S[tt][st][2 * rp]     * inv[st];
                float p1 = S[tt][st][2 * rp + 1] * inv[st];
                unsigned h0 = bf16rn_bits(p0), h1 = bf16rn_bits(p1);
                unsigned l0 = bf16rn_bits(p0 - __uint_as_float(h0));
                unsigned l1 = bf16rn_bits(p1 - __uint_as_float(h1));
                int w = tt * 8 + 2 * g + rp;                    // t-pair index
                int wsw = (((w >> 2) ^ (r15 & 7)) << 2) + (w & 3);
                PHs[wid][r15][wsw] = __builtin_amdgcn_perm(h1, h0, 0x07060302u);
                PLs[wid][r15][wsw] = __builtin_amdgcn_perm(l1, l0, 0x07060302u);
            }
        __syncthreads();
        f32x4 o[2] = {};
        #pragma unroll
        for (int kc = 0; kc < 2; ++kc) {
            int grp = (4 * kc + g) ^ (r15 & 7);
            short8 ph = *(const short8*)&PHs[wid][r15][grp * 4];
            short8 pl = *(const short8*)&PLs[wid][r15][grp * 4];
            #pragma unroll
            for (int dt = 0; dt < 2; ++dt) {
                o[dt] = __builtin_amdgcn_mfma_f32_16x16x32_bf16(ph, vfh[dt][kc], o[dt], 0, 0, 0);
                o[dt] = __builtin_amdgcn_mfma_f32_16x16x32_bf16(ph, vfl[dt][kc], o[dt], 0, 0, 0);
                o[dt] = __builtin_amdgcn_mfma_f32_16x16x32_bf16(pl, vfh[dt][kc], o[dt], 0, 0, 0);
            }
        }
        #pragma unroll
        for (int r = 0; r < 4; ++r) {
            int s = st * 16 + 4 * g + r;
            if (s < SEQ) {
                size_t ob = ((size_t)b2 * SEQ + s) * CDIM + h * HD + r15;
                Yp[ob]      = packsplit(o[0][r]);
                Yp[ob + 16] = packsplit(o[1][r]);
            }
        }
        __syncthreads();
    }
}

extern "C" void kernel_launch(void* const* d_in, const int* in_sizes, int n_in,
                              void* d_out, int out_size, void* d_ws, size_t ws_size,
                              hipStream_t stream) {
    const float* x          = (const float*)d_in[0];
    const float* w_qkv      = (const float*)d_in[1];
    const float* b_qkv      = (const float*)d_in[2];
    const float* bias_table = (const float*)d_in[3];
    const float* w_out      = (const float*)d_in[4];
    const float* b_out      = (const float*)d_in[5];
    unsigned* Tp = (unsigned*)d_ws;                 // 3*QL packed words (925 MB)
    const size_t TPW = 3 * QL;

    const size_t need = TPW * 4ULL + (size_t)NH3 * CDIM * 4ULL + (size_t)CDIM * CDIM * 4ULL;
    const bool big = ws_size >= need;

    if (big) {
        unsigned short* wq_hi = (unsigned short*)((char*)d_ws + TPW * 4ULL);
        unsigned short* wq_lo = wq_hi + (size_t)NH3 * CDIM;
        unsigned short* wo_hi = wq_lo + (size_t)NH3 * CDIM;
        unsigned short* wo_lo = wo_hi + (size_t)CDIM * CDIM;
        unsigned* xp = (unsigned*)d_out;            // packed x in d_out (exact fit)

        prep_w<<<(NH3 * (CDIM / 8) + 255) / 256, 256, 0, stream>>>(w_qkv, wq_hi, wq_lo, NH3, CDIM);
        prep_w<<<(CDIM * (CDIM / 8) + 255) / 256, 256, 0, stream>>>(w_out, wo_hi, wo_lo, CDIM, CDIM);
        prep_x<<<(NTOK * CDIM / 8 + 255) / 256, 256, 0, stream>>>(x, xp, NTOK * CDIM / 8);

        gemm_b3<1, 2, true, false><<<14112, 256, 0, stream>>>(
            nullptr, wq_hi, wq_lo, nullptr, nullptr, nullptr, nullptr, xp,
            b_qkv, nullptr, Tp, NH3, NTOK, CDIM, 9, 1764);

        attn_mfma<<<12288, 256, 0, stream>>>(Tp, bias_table, (unsigned*)d_out);

        gemm_b3<2, 1, false, false><<<dim3(3, 1568), 256, 0, stream>>>(
            nullptr, nullptr, nullptr, (unsigned*)d_out, nullptr, wo_hi, wo_lo, nullptr,
            b_out, nullptr, Tp, NTOK, CDIM, CDIM, 0, 0);

        gemm_b3<2, 1, false, true><<<dim3(3, 1568), 256, 0, stream>>>(
            nullptr, nullptr, nullptr, Tp, nullptr, wo_hi, wo_lo, nullptr,
            b_out, (float*)d_out, nullptr, NTOK, CDIM, CDIM, 0, 0);
    } else {
        // fallback: R3-proven placement; x staged fp32 inline
        unsigned short* wq_hi = (unsigned short*)d_out;
        unsigned short* wq_lo = wq_hi + (size_t)NH3 * CDIM;
        unsigned short* wo_hi = (unsigned short*)(Tp + QL);   // k-third, dead after attn
        unsigned short* wo_lo = wo_hi + (size_t)CDIM * CDIM;

        prep_w<<<(NH3 * (CDIM / 8) + 255) / 256, 256, 0, stream>>>(w_qkv, wq_hi, wq_lo, NH3, CDIM);

        gemm_b3<1, 0, true, false><<<14112, 256, 0, stream>>>(
            nullptr, wq_hi, wq_lo, nullptr, x, nullptr, nullptr, nullptr,
            b_qkv, nullptr, Tp, NH3, NTOK, CDIM, 9, 1764);

        attn_mfma<<<12288, 256, 0, stream>>>(Tp, bias_table, (unsigned*)d_out);

        prep_w<<<(CDIM * (CDIM / 8) + 255) / 256, 256, 0, stream>>>(w_out, wo_hi, wo_lo, CDIM, CDIM);

        gemm_b3<2, 1, false, false><<<dim3(3, 1568), 256, 0, stream>>>(
            nullptr, nullptr, nullptr, (unsigned*)d_out, nullptr, wo_hi, wo_lo, nullptr,
            b_out, nullptr, Tp, NTOK, CDIM, CDIM, 0, 0);

        gemm_b3<2, 1, false, true><<<dim3(3, 1568), 256, 0, stream>>>(
            nullptr, nullptr, nullptr, Tp, nullptr, wo_hi, wo_lo, nullptr,
            b_out, (float*)d_out, nullptr, NTOK, CDIM, CDIM, 0, 0);
    }
}